// Round 10
// baseline (982.513 us; speedup 1.0000x reference)
//
#include <hip/hip_runtime.h>
#include <math.h>

#define SEQT 1024
#define NTOK 2048
#define HIDN 512
#define NHD 8
#define HDIM 64
#define KTSN 4

__device__ __forceinline__ float wred(float v) {
#pragma unroll
  for (int off = 32; off; off >>= 1) v += __shfl_xor(v, off, 64);
  return v;
}

// rotation-allreduce within rows of 16 via DPP (VALU-speed)
template <int CTRL>
__device__ __forceinline__ float rra(float v) {
  return v + __int_as_float(__builtin_amdgcn_update_dpp(
                 0, __float_as_int(v), CTRL, 0xf, 0xf, true));
}
__device__ __forceinline__ float rlane(float v, int l) {
  return __int_as_float(__builtin_amdgcn_readlane(__float_as_int(v), l));
}
// full-wave sum: 4 DPP row_rors (row sums) + 4 readlanes + adds.
// Entirely VALU/SALU: keeps the serial g-chain off the LDS pipe.
__device__ __forceinline__ float wsum64_fast(float v) {
  v = rra<0x121>(v);  // row_ror:1
  v = rra<0x122>(v);  // row_ror:2
  v = rra<0x124>(v);  // row_ror:4
  v = rra<0x128>(v);  // row_ror:8  -> each lane has its 16-lane row sum
  return (rlane(v, 0) + rlane(v, 16)) + (rlane(v, 32) + rlane(v, 48));
}

// ---------------- K1: input RMSNorm (one block per row) ----------------
__global__ __launch_bounds__(256) void k_rmsnorm_in(
    const float* __restrict__ x, const float* __restrict__ w, float* __restrict__ xn) {
  int m = blockIdx.x;
  int tid = threadIdx.x;
  const float* row = x + (size_t)m * HIDN;
  float2 v = *(const float2*)(row + tid * 2);
  float ss = wred(v.x * v.x + v.y * v.y);
  __shared__ float red[4];
  int lane = tid & 63, wv = tid >> 6;
  if (lane == 0) red[wv] = ss;
  __syncthreads();
  float tot = red[0] + red[1] + red[2] + red[3];
  float inv = rsqrtf(tot * (1.0f / HIDN) + 1e-5f);
  float2 wv2 = *(const float2*)(w + tid * 2);
  float2 o;
  o.x = v.x * inv * wv2.x;
  o.y = v.y * inv * wv2.y;
  *(float2*)(xn + (size_t)m * HIDN + tid * 2) = o;
}

// ---------------- K2: C[m][n] = sum_k A[m][k]*B[n][k]  (M=2048, K=512) ----------------
__global__ __launch_bounds__(256) void k_gemm_nt(
    const float* __restrict__ A, const float* __restrict__ B, float* __restrict__ C, int N) {
  __shared__ __align__(16) float As[32][68];
  __shared__ __align__(16) float Bs[32][68];
  int tid = threadIdx.x;
  int m0 = blockIdx.x * 64, n0 = blockIdx.y * 64;
  int tm = tid >> 4, tn = tid & 15;
  float acc[4][4] = {};
  int rr = tid >> 2, cc = (tid & 3) * 8;
  for (int k0 = 0; k0 < HIDN; k0 += 32) {
    const float* s0 = A + (size_t)(m0 + rr) * HIDN + k0 + cc;
    float4 a0 = *(const float4*)s0;
    float4 a1 = *(const float4*)(s0 + 4);
    As[cc + 0][rr] = a0.x; As[cc + 1][rr] = a0.y; As[cc + 2][rr] = a0.z; As[cc + 3][rr] = a0.w;
    As[cc + 4][rr] = a1.x; As[cc + 5][rr] = a1.y; As[cc + 6][rr] = a1.z; As[cc + 7][rr] = a1.w;
    int bn = n0 + rr;
    float4 b0 = make_float4(0.f, 0.f, 0.f, 0.f), b1 = make_float4(0.f, 0.f, 0.f, 0.f);
    if (bn < N) {
      const float* s1 = B + (size_t)bn * HIDN + k0 + cc;
      b0 = *(const float4*)s1;
      b1 = *(const float4*)(s1 + 4);
    }
    Bs[cc + 0][rr] = b0.x; Bs[cc + 1][rr] = b0.y; Bs[cc + 2][rr] = b0.z; Bs[cc + 3][rr] = b0.w;
    Bs[cc + 4][rr] = b1.x; Bs[cc + 5][rr] = b1.y; Bs[cc + 6][rr] = b1.z; Bs[cc + 7][rr] = b1.w;
    __syncthreads();
#pragma unroll
    for (int kk = 0; kk < 32; ++kk) {
      float4 a4 = *(const float4*)&As[kk][tm * 4];
      float4 b4 = *(const float4*)&Bs[kk][tn * 4];
      float aa[4] = {a4.x, a4.y, a4.z, a4.w};
      float bb[4] = {b4.x, b4.y, b4.z, b4.w};
#pragma unroll
      for (int i = 0; i < 4; ++i)
#pragma unroll
        for (int j = 0; j < 4; ++j) acc[i][j] += aa[i] * bb[j];
    }
    __syncthreads();
  }
#pragma unroll
  for (int i = 0; i < 4; ++i) {
    int mr = m0 + tm * 4 + i;
#pragma unroll
    for (int j = 0; j < 4; ++j) {
      int nc = n0 + tn * 4 + j;
      if (nc < N) C[(size_t)mr * N + nc] = acc[i][j];
    }
  }
}

// ---------------- K3a: rope cos/sin table [t][j] ----------------
__global__ __launch_bounds__(256) void k_rope_table(float2* __restrict__ tab) {
  int idx = blockIdx.x * 256 + threadIdx.x;  // 1024*32
  int t = idx >> 5, j = idx & 31;
  float invf = (float)exp2(-(double)j * (13.287712379549449 / 32.0));  // 10000^(-j/32)
  float ang = (float)t * invf;                                         // fp32, matches ref
  double s, c;
  sincos((double)ang, &s, &c);
  tab[idx] = make_float2((float)c, (float)s);
}

// ---------------- K3b: rope(q,k), rmsnorm(k), rmsnorm(v), alpha, mix; transpose ----------------
__global__ __launch_bounds__(256) void k_postproc(
    const float* __restrict__ q_in, const float* __restrict__ k_in, const float* __restrict__ v_in,
    const float* __restrict__ a_pre, const float* __restrict__ m_pre,
    const float* __restrict__ ab, const float* __restrict__ mb,
    const float* __restrict__ kn_w, const float* __restrict__ vn_w,
    const float2* __restrict__ tab,
    float* __restrict__ qh, float* __restrict__ kh, float* __restrict__ vh,
    float* __restrict__ av, float* __restrict__ mv) {
  int wid = blockIdx.x * 4 + (threadIdx.x >> 6);  // one wave per (b,t,h)
  int lane = threadIdx.x & 63;
  int b = wid >> 13;
  int rem = wid & 8191;
  int t = rem >> 3;
  int h = rem & 7;
  size_t src = (size_t)(b * SEQT + t) * HIDN + h * HDIM + lane;
  float qv = q_in[src], kv = k_in[src], vv = v_in[src];
  float2 cs = tab[t * 32 + (lane & 31)];
  float qpart = __shfl_xor(qv, 32, 64);
  float kpart = __shfl_xor(kv, 32, 64);
  float qr = (lane < 32) ? (qv * cs.x - qpart * cs.y) : (qpart * cs.y + qv * cs.x);
  float kr = (lane < 32) ? (kv * cs.x - kpart * cs.y) : (kpart * cs.y + kv * cs.x);
  float kss = wred(kr * kr);
  float kn = kr * rsqrtf(kss * (1.0f / HDIM) + 1e-5f) * kn_w[lane];
  float vss = wred(vv * vv);
  float vn = vv * rsqrtf(vss * (1.0f / HDIM) + 1e-5f) * vn_w[lane];
  size_t dst = ((size_t)(b * NHD + h) * SEQT + t) * HDIM + lane;
  qh[dst] = qr;
  kh[dst] = kn;
  vh[dst] = vn;
  if (lane < 4) {
    int col = h * 4 + lane;
    float pa = a_pre[(size_t)(b * SEQT + t) * 32 + col] + ab[col];
    float al = 1.0f / (1.0f + expf(-pa));
    al = fminf(fmaxf(al, 1e-4f), 0.9995f);
    float pm = m_pre[(size_t)(b * SEQT + t) * 32 + col] + mb[col];
    float mx = pm;
    mx = fmaxf(mx, __shfl_xor(mx, 1, 64));
    mx = fmaxf(mx, __shfl_xor(mx, 2, 64));
    float e = expf(pm - mx);
    float sum = e;
    sum += __shfl_xor(sum, 1, 64);
    sum += __shfl_xor(sum, 2, 64);
    size_t adst = ((size_t)(b * NHD + h) * KTSN + lane) * SEQT + t;
    av[adst] = al;
    mv[adst] = e / sum;
  }
}

// ---------------- K4: sequential scan, ONE WAVE per (b,h,kt) cell ----------------
// NO LDS AT ALL. Lane l prefetches k[t,l]/q[t,l]/v[t,l] (coalesced); the
// wave-uniform k[d]/q[d] scalars are produced by v_readlane (constant lane
// index -> SGPR) and consumed directly as the one-SGPR operand of v_fma.
// This removes every lgkmcnt stall from the serial chain: the step is pure
// VALU issue (~256 FMA-class + 128 readlane), with global prefetch (t+1)
// hidden under it. h-state = 64 named scalar floats (r6-proven promotable).
#define G16(X) \
  X(0) X(1) X(2) X(3) X(4) X(5) X(6) X(7) \
  X(8) X(9) X(10) X(11) X(12) X(13) X(14) X(15)

#define DECLH(g) \
  float h##g##_0 = 0.f, h##g##_1 = 0.f, h##g##_2 = 0.f, h##g##_3 = 0.f;

#define UPDH(g)                                     \
  {                                                 \
    float ks0 = rlane(kC, 4 * (g) + 0);             \
    float ks1 = rlane(kC, 4 * (g) + 1);             \
    float ks2 = rlane(kC, 4 * (g) + 2);             \
    float ks3 = rlane(kC, 4 * (g) + 3);             \
    h##g##_0 = fmaf(h##g##_0, ag, ks0 * vem);       \
    h##g##_1 = fmaf(h##g##_1, ag, ks1 * vem);       \
    h##g##_2 = fmaf(h##g##_2, ag, ks2 * vem);       \
    h##g##_3 = fmaf(h##g##_3, ag, ks3 * vem);       \
    sq0 = fmaf(h##g##_0, h##g##_0, sq0);            \
    sq1 = fmaf(h##g##_1, h##g##_1, sq1);            \
    sq2 = fmaf(h##g##_2, h##g##_2, sq2);            \
    sq3 = fmaf(h##g##_3, h##g##_3, sq3);            \
  }

#define YUPH(g)                                     \
  {                                                 \
    float qs0 = rlane(qC, 4 * (g) + 0);             \
    float qs1 = rlane(qC, 4 * (g) + 1);             \
    float qs2 = rlane(qC, 4 * (g) + 2);             \
    float qs3 = rlane(qC, 4 * (g) + 3);             \
    y0 = fmaf(qs0, h##g##_0, y0);                   \
    y1 = fmaf(qs1, h##g##_1, y1);                   \
    y2 = fmaf(qs2, h##g##_2, y2);                   \
    y3 = fmaf(qs3, h##g##_3, y3);                   \
  }

__global__ __launch_bounds__(64, 1) __attribute__((amdgpu_waves_per_eu(1)))
void k_scan(
    const float* __restrict__ qh, const float* __restrict__ kh, const float* __restrict__ vh,
    const float* __restrict__ av, const float* __restrict__ mv, const int* __restrict__ mask,
    float* __restrict__ y0p, float* __restrict__ y1p, float* __restrict__ y2p,
    float* __restrict__ y3p) {
  int c = blockIdx.x;  // (b*NH+h)*KTS + kt
  int kt = c & 3;
  int bh = c >> 2;
  int b = bh >> 3;
  int h = bh & 7;
  int lane = threadIdx.x;  // 0..63, = e (and = d for the per-lane k/q loads)

  const float* kp = kh + (size_t)bh * SEQT * HDIM;
  const float* qp = qh + (size_t)bh * SEQT * HDIM;
  const float* vp = vh + (size_t)bh * SEQT * HDIM;
  const float* ap = av + (size_t)c * SEQT;
  const float* mp = mv + (size_t)c * SEQT;
  const int* mk = mask + (size_t)b * SEQT;
  float* ysel = (kt == 0) ? y0p : (kt == 1) ? y1p : (kt == 2) ? y2p : y3p;
  float* ypo = ysel + (size_t)(b * SEQT) * HIDN + h * HDIM + lane;

  G16(DECLH)  // h0_0..h15_3 = 64 named floats, all zero
  float gprev = 1.0f;

  // prologue: per-lane load of step 0 (lane l holds k[0,l], q[0,l], v[0,l])
  float kC = kp[lane];
  float qC = qp[lane];
  float vC = vp[lane];
  float aC = ap[0], mxC = mp[0];
  float mC = (float)mk[0];

  for (int t = 0; t < SEQT; ++t) {
    // per-lane global prefetch of t+1 (latency hidden under this step's VALU)
    int tn = t + 1;
    if (tn > SEQT - 1) tn = SEQT - 1;
    float kN = kp[(size_t)tn * HDIM + lane];
    float qN = qp[(size_t)tn * HDIM + lane];
    float vN = vp[(size_t)tn * HDIM + lane];
    float aN = ap[tn];
    float mxN = mp[tn];
    float mN = (float)mk[tn];

    float ag = aC * gprev;  // deferred norm scale folded into alpha
    float vem = vC * mC;    // mask folded into v
    float sq0 = 0.f, sq1 = 0.f, sq2 = 0.f, sq3 = 0.f;
    G16(UPDH)  // 64 readlane + 128 FMA-class, register-only
    float sq = wsum64_fast(((sq0 + sq1) + (sq2 + sq3)));
    float g = fminf(16.0f * rsqrtf(sq), 1.0f);  // c=sqrt(64)*2; sq=0 -> 1
    float y0 = 0.f, y1 = 0.f, y2 = 0.f, y3 = 0.f;
    G16(YUPH)  // 64 readlane + 64 FMA; independent of the g-chain above
    ypo[(size_t)t * HIDN] = (mxC * g) * ((y0 + y1) + (y2 + y3));
    gprev = g;

    kC = kN;
    qC = qN;
    vC = vN;
    aC = aN;
    mxC = mxN;
    mC = mN;
  }
}

// ---------------- K5: r = x + (sum_kt y) @ oW^T + ob ----------------
__global__ __launch_bounds__(256) void k_gemm_out(
    const float* __restrict__ y0, const float* __restrict__ y1,
    const float* __restrict__ y2, const float* __restrict__ y3,
    const float* __restrict__ oW, const float* __restrict__ ob,
    const float* __restrict__ x, float* __restrict__ r) {
  __shared__ __align__(16) float As[32][68];
  __shared__ __align__(16) float Bs[32][68];
  int tid = threadIdx.x;
  int m0 = blockIdx.x * 64, n0 = blockIdx.y * 64;
  int tm = tid >> 4, tn = tid & 15;
  float acc[4][4] = {};
  int rr = tid >> 2, cc = (tid & 3) * 8;
  for (int k0 = 0; k0 < HIDN; k0 += 32) {
    size_t aoff = (size_t)(m0 + rr) * HIDN + k0 + cc;
#pragma unroll
    for (int half = 0; half < 2; ++half) {
      size_t sh = aoff + half * 4;
      float4 p0 = *(const float4*)(y0 + sh);
      float4 p1 = *(const float4*)(y1 + sh);
      float4 p2 = *(const float4*)(y2 + sh);
      float4 p3 = *(const float4*)(y3 + sh);
      int cbase = cc + half * 4;
      As[cbase + 0][rr] = p0.x + p1.x + p2.x + p3.x;
      As[cbase + 1][rr] = p0.y + p1.y + p2.y + p3.y;
      As[cbase + 2][rr] = p0.z + p1.z + p2.z + p3.z;
      As[cbase + 3][rr] = p0.w + p1.w + p2.w + p3.w;
    }
    const float* s1 = oW + (size_t)(n0 + rr) * HIDN + k0 + cc;
    float4 b0 = *(const float4*)s1;
    float4 b1 = *(const float4*)(s1 + 4);
    Bs[cc + 0][rr] = b0.x; Bs[cc + 1][rr] = b0.y; Bs[cc + 2][rr] = b0.z; Bs[cc + 3][rr] = b0.w;
    Bs[cc + 4][rr] = b1.x; Bs[cc + 5][rr] = b1.y; Bs[cc + 6][rr] = b1.z; Bs[cc + 7][rr] = b1.w;
    __syncthreads();
#pragma unroll
    for (int kk = 0; kk < 32; ++kk) {
      float4 a4 = *(const float4*)&As[kk][tm * 4];
      float4 b4 = *(const float4*)&Bs[kk][tn * 4];
      float aa[4] = {a4.x, a4.y, a4.z, a4.w};
      float bb[4] = {b4.x, b4.y, b4.z, b4.w};
#pragma unroll
      for (int i = 0; i < 4; ++i)
#pragma unroll
        for (int j = 0; j < 4; ++j) acc[i][j] += aa[i] * bb[j];
    }
    __syncthreads();
  }
#pragma unroll
  for (int i = 0; i < 4; ++i) {
    int mr = m0 + tm * 4 + i;
#pragma unroll
    for (int j = 0; j < 4; ++j) {
      int nc = n0 + tn * 4 + j;
      r[(size_t)mr * HIDN + nc] = x[(size_t)mr * HIDN + nc] + acc[i][j] + ob[nc];
    }
  }
}

// ---------------- K6: LayerNorm -> out ----------------
__global__ __launch_bounds__(256) void k_layernorm(
    const float* __restrict__ r, const float* __restrict__ w, const float* __restrict__ bb,
    float* __restrict__ out) {
  int m = blockIdx.x;
  int tid = threadIdx.x;
  const float* row = r + (size_t)m * HIDN;
  float2 v = *(const float2*)(row + tid * 2);
  float s = wred(v.x + v.y);
  float ss = wred(v.x * v.x + v.y * v.y);
  __shared__ float r1[4], r2[4];
  int lane = tid & 63, wv = tid >> 6;
  if (lane == 0) {
    r1[wv] = s;
    r2[wv] = ss;
  }
  __syncthreads();
  float S = r1[0] + r1[1] + r1[2] + r1[3];
  float SS = r2[0] + r2[1] + r2[2] + r2[3];
  float mu = S * (1.0f / HIDN);
  float var = SS * (1.0f / HIDN) - mu * mu;
  float inv = rsqrtf(var + 1e-5f);
  float2 w2 = *(const float2*)(w + tid * 2);
  float2 b2 = *(const float2*)(bb + tid * 2);
  float2 o;
  o.x = (v.x - mu) * inv * w2.x + b2.x;
  o.y = (v.y - mu) * inv * w2.y + b2.y;
  *(float2*)(out + (size_t)m * HIDN + tid * 2) = o;
}

// ---------------- launch ----------------
extern "C" void kernel_launch(void* const* d_in, const int* in_sizes, int n_in,
                              void* d_out, int out_size, void* d_ws, size_t ws_size,
                              hipStream_t stream) {
  const float* x = (const float*)d_in[0];
  const float* in_w = (const float*)d_in[1];
  const float* qW = (const float*)d_in[2];
  const float* kW = (const float*)d_in[3];
  const float* vW = (const float*)d_in[4];
  const float* aW = (const float*)d_in[5];
  const float* ab = (const float*)d_in[6];
  const float* mW = (const float*)d_in[7];
  const float* mb = (const float*)d_in[8];
  const float* oW = (const float*)d_in[9];
  const float* ob = (const float*)d_in[10];
  const float* kn_w = (const float*)d_in[11];
  const float* vn_w = (const float*)d_in[12];
  const float* ln_w = (const float*)d_in[13];
  const float* ln_b = (const float*)d_in[14];
  const int* mask = (const int*)d_in[15];

  float* ws = (float*)d_ws;
  // Layout (floats). No live overlap:
  //   xn    [0        , 1048576 )  dead after 5 GEMMs -> reused as rr
  //   qb    [1048576  , 2097152 )  dead after postproc -> reused as y0
  //   kb    [2097152  , 3145728 )  dead after postproc -> reused as y1
  //   vb    [3145728  , 4194304 )  dead after postproc -> reused as y2
  //   apre  [4194304  , 4259840 )
  //   mpre  [4259840  , 4325376 )
  //   tab   [4325376  , 4390912 )
  //   qh    [4390912  , 5439488 )
  //   kh    [5439488  , 6488064 )
  //   vh    [6488064  , 7536640 )
  //   avv   [7536640  , 7602176 )
  //   mvv   [7602176  , 7667712 )
  //   y3    [7667712  , 8716288 )   total ~34.9 MB
  float* xn = ws + 0;
  float* qb = ws + 1048576;
  float* kb = ws + 2097152;
  float* vb = ws + 3145728;
  float* apre = ws + 4194304;
  float* mpre = ws + 4259840;
  float2* tab = (float2*)(ws + 4325376);
  float* qh = ws + 4390912;
  float* kh = ws + 5439488;
  float* vh = ws + 6488064;
  float* avv = ws + 7536640;
  float* mvv = ws + 7602176;
  float* y3 = ws + 7667712;
  float* y0 = qb;
  float* y1 = kb;
  float* y2 = vb;
  float* rr = xn;

  k_rmsnorm_in<<<NTOK, 256, 0, stream>>>(x, in_w, xn);
  k_rope_table<<<128, 256, 0, stream>>>(tab);
  dim3 gBig(32, 8);
  k_gemm_nt<<<gBig, 256, 0, stream>>>(xn, qW, qb, 512);
  k_gemm_nt<<<gBig, 256, 0, stream>>>(xn, kW, kb, 512);
  k_gemm_nt<<<gBig, 256, 0, stream>>>(xn, vW, vb, 512);
  dim3 gSmall(32, 1);
  k_gemm_nt<<<gSmall, 256, 0, stream>>>(xn, aW, apre, 32);
  k_gemm_nt<<<gSmall, 256, 0, stream>>>(xn, mW, mpre, 32);
  k_postproc<<<4096, 256, 0, stream>>>(qb, kb, vb, apre, mpre, ab, mb, kn_w, vn_w, tab,
                                       qh, kh, vh, avv, mvv);
  k_scan<<<64, 64, 0, stream>>>(qh, kh, vh, avv, mvv, mask, y0, y1, y2, y3);
  k_gemm_out<<<gBig, 256, 0, stream>>>(y0, y1, y2, y3, oW, ob, x, rr);
  k_layernorm<<<NTOK, 256, 0, stream>>>(rr, ln_w, ln_b, (float*)d_out);
  (void)in_sizes; (void)n_in; (void)out_size; (void)ws_size;
}

// Round 11
// 880.594 us; speedup vs baseline: 1.1157x; 1.1157x over previous
//
#include <hip/hip_runtime.h>
#include <math.h>

#define SEQT 1024
#define NTOK 2048
#define HIDN 512
#define NHD 8
#define HDIM 64
#define KTSN 4

__device__ __forceinline__ float wred(float v) {
#pragma unroll
  for (int off = 32; off; off >>= 1) v += __shfl_xor(v, off, 64);
  return v;
}

// rotation-allreduce within rows of 16 via DPP (VALU-speed)
template <int CTRL>
__device__ __forceinline__ float rra(float v) {
  return v + __int_as_float(__builtin_amdgcn_update_dpp(
                 0, __float_as_int(v), CTRL, 0xf, 0xf, true));
}
__device__ __forceinline__ float rlane(float v, int l) {
  return __int_as_float(__builtin_amdgcn_readlane(__float_as_int(v), l));
}
// full-wave sum: 4 DPP row_rors (row sums) + 4 readlanes + adds.
__device__ __forceinline__ float wsum64_fast(float v) {
  v = rra<0x121>(v);  // row_ror:1
  v = rra<0x122>(v);  // row_ror:2
  v = rra<0x124>(v);  // row_ror:4
  v = rra<0x128>(v);  // row_ror:8  -> each lane has its 16-lane row sum
  return (rlane(v, 0) + rlane(v, 16)) + (rlane(v, 32) + rlane(v, 48));
}

// ---------------- K1: input RMSNorm (one block per row) ----------------
__global__ __launch_bounds__(256) void k_rmsnorm_in(
    const float* __restrict__ x, const float* __restrict__ w, float* __restrict__ xn) {
  int m = blockIdx.x;
  int tid = threadIdx.x;
  const float* row = x + (size_t)m * HIDN;
  float2 v = *(const float2*)(row + tid * 2);
  float ss = wred(v.x * v.x + v.y * v.y);
  __shared__ float red[4];
  int lane = tid & 63, wv = tid >> 6;
  if (lane == 0) red[wv] = ss;
  __syncthreads();
  float tot = red[0] + red[1] + red[2] + red[3];
  float inv = rsqrtf(tot * (1.0f / HIDN) + 1e-5f);
  float2 wv2 = *(const float2*)(w + tid * 2);
  float2 o;
  o.x = v.x * inv * wv2.x;
  o.y = v.y * inv * wv2.y;
  *(float2*)(xn + (size_t)m * HIDN + tid * 2) = o;
}

// ---------------- K2: C[m][n] = sum_k A[m][k]*B[n][k]  (M=2048, K=512) ----------------
__global__ __launch_bounds__(256) void k_gemm_nt(
    const float* __restrict__ A, const float* __restrict__ B, float* __restrict__ C, int N) {
  __shared__ __align__(16) float As[32][68];
  __shared__ __align__(16) float Bs[32][68];
  int tid = threadIdx.x;
  int m0 = blockIdx.x * 64, n0 = blockIdx.y * 64;
  int tm = tid >> 4, tn = tid & 15;
  float acc[4][4] = {};
  int rr = tid >> 2, cc = (tid & 3) * 8;
  for (int k0 = 0; k0 < HIDN; k0 += 32) {
    const float* s0 = A + (size_t)(m0 + rr) * HIDN + k0 + cc;
    float4 a0 = *(const float4*)s0;
    float4 a1 = *(const float4*)(s0 + 4);
    As[cc + 0][rr] = a0.x; As[cc + 1][rr] = a0.y; As[cc + 2][rr] = a0.z; As[cc + 3][rr] = a0.w;
    As[cc + 4][rr] = a1.x; As[cc + 5][rr] = a1.y; As[cc + 6][rr] = a1.z; As[cc + 7][rr] = a1.w;
    int bn = n0 + rr;
    float4 b0 = make_float4(0.f, 0.f, 0.f, 0.f), b1 = make_float4(0.f, 0.f, 0.f, 0.f);
    if (bn < N) {
      const float* s1 = B + (size_t)bn * HIDN + k0 + cc;
      b0 = *(const float4*)s1;
      b1 = *(const float4*)(s1 + 4);
    }
    Bs[cc + 0][rr] = b0.x; Bs[cc + 1][rr] = b0.y; Bs[cc + 2][rr] = b0.z; Bs[cc + 3][rr] = b0.w;
    Bs[cc + 4][rr] = b1.x; Bs[cc + 5][rr] = b1.y; Bs[cc + 6][rr] = b1.z; Bs[cc + 7][rr] = b1.w;
    __syncthreads();
#pragma unroll
    for (int kk = 0; kk < 32; ++kk) {
      float4 a4 = *(const float4*)&As[kk][tm * 4];
      float4 b4 = *(const float4*)&Bs[kk][tn * 4];
      float aa[4] = {a4.x, a4.y, a4.z, a4.w};
      float bb[4] = {b4.x, b4.y, b4.z, b4.w};
#pragma unroll
      for (int i = 0; i < 4; ++i)
#pragma unroll
        for (int j = 0; j < 4; ++j) acc[i][j] += aa[i] * bb[j];
    }
    __syncthreads();
  }
#pragma unroll
  for (int i = 0; i < 4; ++i) {
    int mr = m0 + tm * 4 + i;
#pragma unroll
    for (int j = 0; j < 4; ++j) {
      int nc = n0 + tn * 4 + j;
      if (nc < N) C[(size_t)mr * N + nc] = acc[i][j];
    }
  }
}

// ---------------- K3a: rope cos/sin table [t][j] ----------------
__global__ __launch_bounds__(256) void k_rope_table(float2* __restrict__ tab) {
  int idx = blockIdx.x * 256 + threadIdx.x;  // 1024*32
  int t = idx >> 5, j = idx & 31;
  float invf = (float)exp2(-(double)j * (13.287712379549449 / 32.0));  // 10000^(-j/32)
  float ang = (float)t * invf;                                         // fp32, matches ref
  double s, c;
  sincos((double)ang, &s, &c);
  tab[idx] = make_float2((float)c, (float)s);
}

// ---------------- K3b: rope(q,k), rmsnorm(k), rmsnorm(v), alpha, mix; transpose ----------------
__global__ __launch_bounds__(256) void k_postproc(
    const float* __restrict__ q_in, const float* __restrict__ k_in, const float* __restrict__ v_in,
    const float* __restrict__ a_pre, const float* __restrict__ m_pre,
    const float* __restrict__ ab, const float* __restrict__ mb,
    const float* __restrict__ kn_w, const float* __restrict__ vn_w,
    const float2* __restrict__ tab,
    float* __restrict__ qh, float* __restrict__ kh, float* __restrict__ vh,
    float* __restrict__ av, float* __restrict__ mv) {
  int wid = blockIdx.x * 4 + (threadIdx.x >> 6);  // one wave per (b,t,h)
  int lane = threadIdx.x & 63;
  int b = wid >> 13;
  int rem = wid & 8191;
  int t = rem >> 3;
  int h = rem & 7;
  size_t src = (size_t)(b * SEQT + t) * HIDN + h * HDIM + lane;
  float qv = q_in[src], kv = k_in[src], vv = v_in[src];
  float2 cs = tab[t * 32 + (lane & 31)];
  float qpart = __shfl_xor(qv, 32, 64);
  float kpart = __shfl_xor(kv, 32, 64);
  float qr = (lane < 32) ? (qv * cs.x - qpart * cs.y) : (qpart * cs.y + qv * cs.x);
  float kr = (lane < 32) ? (kv * cs.x - kpart * cs.y) : (kpart * cs.y + kv * cs.x);
  float kss = wred(kr * kr);
  float kn = kr * rsqrtf(kss * (1.0f / HDIM) + 1e-5f) * kn_w[lane];
  float vss = wred(vv * vv);
  float vn = vv * rsqrtf(vss * (1.0f / HDIM) + 1e-5f) * vn_w[lane];
  size_t dst = ((size_t)(b * NHD + h) * SEQT + t) * HDIM + lane;
  qh[dst] = qr;
  kh[dst] = kn;
  vh[dst] = vn;
  if (lane < 4) {
    int col = h * 4 + lane;
    float pa = a_pre[(size_t)(b * SEQT + t) * 32 + col] + ab[col];
    float al = 1.0f / (1.0f + expf(-pa));
    al = fminf(fmaxf(al, 1e-4f), 0.9995f);
    float pm = m_pre[(size_t)(b * SEQT + t) * 32 + col] + mb[col];
    float mx = pm;
    mx = fmaxf(mx, __shfl_xor(mx, 1, 64));
    mx = fmaxf(mx, __shfl_xor(mx, 2, 64));
    float e = expf(pm - mx);
    float sum = e;
    sum += __shfl_xor(sum, 1, 64);
    sum += __shfl_xor(sum, 2, 64);
    size_t adst = ((size_t)(b * NHD + h) * KTSN + lane) * SEQT + t;
    av[adst] = al;
    mv[adst] = e / sum;
  }
}

// ---------------- K4: sequential scan, FOUR WAVES per (b,h,kt) cell ----------------
// Wave w owns d in [16w, 16w+16); lane = e. h-state = 16 named floats/lane
// (small, promotion-proven). k/q broadcast: lanes 0-15 of each wave hold the
// wave's k-slice, lanes 16-31 the q-slice (one register), broadcast by
// v_readlane. One __syncthreads per step with DOUBLE-BUFFERED LDS exchange
// (parity t&1): waves write sq-partial + y-partial, barrier, all waves
// compute g locally (identical), wave 0 combines y and stores. WAR across
// steps is separated by the next step's barrier.
#define G16(X) \
  X(0, 0) X(1, 1) X(2, 2) X(3, 3) X(4, 0) X(5, 1) X(6, 2) X(7, 3) \
  X(8, 0) X(9, 1) X(10, 2) X(11, 3) X(12, 0) X(13, 1) X(14, 2) X(15, 3)

#define DECLH(g, a) float h##g = 0.f;

#define UPDH(g, a)                                \
  {                                               \
    float ks = rlane(kqC, g);                     \
    h##g = fmaf(h##g, ag, ks * vem);              \
    sq##a = fmaf(h##g, h##g, sq##a);              \
  }

#define YUPH(g, a)                                \
  {                                               \
    float qs = rlane(kqC, 16 + (g));              \
    y##a = fmaf(qs, h##g, y##a);                  \
  }

__global__ __launch_bounds__(256, 1) void k_scan(
    const float* __restrict__ qh, const float* __restrict__ kh, const float* __restrict__ vh,
    const float* __restrict__ av, const float* __restrict__ mv, const int* __restrict__ mask,
    float* __restrict__ y0p, float* __restrict__ y1p, float* __restrict__ y2p,
    float* __restrict__ y3p) {
  int c = blockIdx.x;  // (b*NH+h)*KTS + kt
  int kt = c & 3;
  int bh = c >> 2;
  int b = bh >> 3;
  int h = bh & 7;
  int tid = threadIdx.x;
  int w = tid >> 6;    // wave id: owns d in [16w, 16w+16)
  int lane = tid & 63; // = e
  int dbase = w * 16;

  const float* kp = kh + (size_t)bh * SEQT * HDIM;
  const float* qp = qh + (size_t)bh * SEQT * HDIM;
  const float* vp = vh + (size_t)bh * SEQT * HDIM;
  const float* ap = av + (size_t)c * SEQT;
  const float* mp = mv + (size_t)c * SEQT;
  const int* mk = mask + (size_t)b * SEQT;
  float* ysel = (kt == 0) ? y0p : (kt == 1) ? y1p : (kt == 2) ? y2p : y3p;
  float* ypo = ysel + (size_t)(b * SEQT) * HIDN + h * HDIM + lane;

  __shared__ float sqb[2][4];
  __shared__ __align__(16) float ypart[2][4][64];

  G16(DECLH)  // h0..h15
  float gprev = 1.0f;

  // lanes 0-15: k-slice; lanes 16-31: q-slice; lanes 32-63 duplicate 0-31.
  int off = lane & 15;
  const float* kqbase = ((lane >> 4) & 1) ? qp : kp;
  float kqC = kqbase[dbase + off];
  float vC = vp[lane];
  float aC = ap[0], mxC = mp[0];
  float mC = (float)mk[0];

  for (int t = 0; t < SEQT; ++t) {
    int tn = t + 1;
    if (tn > SEQT - 1) tn = SEQT - 1;
    float kqN = kqbase[(size_t)tn * HDIM + dbase + off];
    float vN = vp[(size_t)tn * HDIM + lane];
    float aN = ap[tn];
    float mxN = mp[tn];
    float mN = (float)mk[tn];

    float ag = aC * gprev;  // deferred norm scale folded into alpha
    float vem = vC * mC;    // mask folded into v
    float sq0 = 0.f, sq1 = 0.f, sq2 = 0.f, sq3 = 0.f;
    G16(UPDH)  // 16 readlane + 32 FMA-class, register-only
    float sqw = wsum64_fast((sq0 + sq1) + (sq2 + sq3));
    float y0 = 0.f, y1 = 0.f, y2 = 0.f, y3 = 0.f;
    G16(YUPH)  // 16 readlane + 16 FMA
    float yp = (y0 + y1) + (y2 + y3);

    int P = t & 1;
    if (lane == 0) sqb[P][w] = sqw;
    ypart[P][w][lane] = yp;
    __syncthreads();
    float sqt = (sqb[P][0] + sqb[P][1]) + (sqb[P][2] + sqb[P][3]);
    float g = fminf(16.0f * rsqrtf(sqt), 1.0f);  // c=sqrt(64)*2; sq=0 -> 1
    if (w == 0) {
      float ys = (ypart[P][0][lane] + ypart[P][1][lane]) +
                 (ypart[P][2][lane] + ypart[P][3][lane]);
      ypo[(size_t)t * HIDN] = (mxC * g) * ys;
    }
    gprev = g;

    kqC = kqN;
    vC = vN;
    aC = aN;
    mxC = mxN;
    mC = mN;
  }
}

// ---------------- K5: r = x + (sum_kt y) @ oW^T + ob ----------------
__global__ __launch_bounds__(256) void k_gemm_out(
    const float* __restrict__ y0, const float* __restrict__ y1,
    const float* __restrict__ y2, const float* __restrict__ y3,
    const float* __restrict__ oW, const float* __restrict__ ob,
    const float* __restrict__ x, float* __restrict__ r) {
  __shared__ __align__(16) float As[32][68];
  __shared__ __align__(16) float Bs[32][68];
  int tid = threadIdx.x;
  int m0 = blockIdx.x * 64, n0 = blockIdx.y * 64;
  int tm = tid >> 4, tn = tid & 15;
  float acc[4][4] = {};
  int rr = tid >> 2, cc = (tid & 3) * 8;
  for (int k0 = 0; k0 < HIDN; k0 += 32) {
    size_t aoff = (size_t)(m0 + rr) * HIDN + k0 + cc;
#pragma unroll
    for (int half = 0; half < 2; ++half) {
      size_t sh = aoff + half * 4;
      float4 p0 = *(const float4*)(y0 + sh);
      float4 p1 = *(const float4*)(y1 + sh);
      float4 p2 = *(const float4*)(y2 + sh);
      float4 p3 = *(const float4*)(y3 + sh);
      int cbase = cc + half * 4;
      As[cbase + 0][rr] = p0.x + p1.x + p2.x + p3.x;
      As[cbase + 1][rr] = p0.y + p1.y + p2.y + p3.y;
      As[cbase + 2][rr] = p0.z + p1.z + p2.z + p3.z;
      As[cbase + 3][rr] = p0.w + p1.w + p2.w + p3.w;
    }
    const float* s1 = oW + (size_t)(n0 + rr) * HIDN + k0 + cc;
    float4 b0 = *(const float4*)s1;
    float4 b1 = *(const float4*)(s1 + 4);
    Bs[cc + 0][rr] = b0.x; Bs[cc + 1][rr] = b0.y; Bs[cc + 2][rr] = b0.z; Bs[cc + 3][rr] = b0.w;
    Bs[cc + 4][rr] = b1.x; Bs[cc + 5][rr] = b1.y; Bs[cc + 6][rr] = b1.z; Bs[cc + 7][rr] = b1.w;
    __syncthreads();
#pragma unroll
    for (int kk = 0; kk < 32; ++kk) {
      float4 a4 = *(const float4*)&As[kk][tm * 4];
      float4 b4 = *(const float4*)&Bs[kk][tn * 4];
      float aa[4] = {a4.x, a4.y, a4.z, a4.w};
      float bb[4] = {b4.x, b4.y, b4.z, b4.w};
#pragma unroll
      for (int i = 0; i < 4; ++i)
#pragma unroll
        for (int j = 0; j < 4; ++j) acc[i][j] += aa[i] * bb[j];
    }
    __syncthreads();
  }
#pragma unroll
  for (int i = 0; i < 4; ++i) {
    int mr = m0 + tm * 4 + i;
#pragma unroll
    for (int j = 0; j < 4; ++j) {
      int nc = n0 + tn * 4 + j;
      r[(size_t)mr * HIDN + nc] = x[(size_t)mr * HIDN + nc] + acc[i][j] + ob[nc];
    }
  }
}

// ---------------- K6: LayerNorm -> out ----------------
__global__ __launch_bounds__(256) void k_layernorm(
    const float* __restrict__ r, const float* __restrict__ w, const float* __restrict__ bb,
    float* __restrict__ out) {
  int m = blockIdx.x;
  int tid = threadIdx.x;
  const float* row = r + (size_t)m * HIDN;
  float2 v = *(const float2*)(row + tid * 2);
  float s = wred(v.x + v.y);
  float ss = wred(v.x * v.x + v.y * v.y);
  __shared__ float r1[4], r2[4];
  int lane = tid & 63, wv = tid >> 6;
  if (lane == 0) {
    r1[wv] = s;
    r2[wv] = ss;
  }
  __syncthreads();
  float S = r1[0] + r1[1] + r1[2] + r1[3];
  float SS = r2[0] + r2[1] + r2[2] + r2[3];
  float mu = S * (1.0f / HIDN);
  float var = SS * (1.0f / HIDN) - mu * mu;
  float inv = rsqrtf(var + 1e-5f);
  float2 w2 = *(const float2*)(w + tid * 2);
  float2 b2 = *(const float2*)(bb + tid * 2);
  float2 o;
  o.x = (v.x - mu) * inv * w2.x + b2.x;
  o.y = (v.y - mu) * inv * w2.y + b2.y;
  *(float2*)(out + (size_t)m * HIDN + tid * 2) = o;
}

// ---------------- launch ----------------
extern "C" void kernel_launch(void* const* d_in, const int* in_sizes, int n_in,
                              void* d_out, int out_size, void* d_ws, size_t ws_size,
                              hipStream_t stream) {
  const float* x = (const float*)d_in[0];
  const float* in_w = (const float*)d_in[1];
  const float* qW = (const float*)d_in[2];
  const float* kW = (const float*)d_in[3];
  const float* vW = (const float*)d_in[4];
  const float* aW = (const float*)d_in[5];
  const float* ab = (const float*)d_in[6];
  const float* mW = (const float*)d_in[7];
  const float* mb = (const float*)d_in[8];
  const float* oW = (const float*)d_in[9];
  const float* ob = (const float*)d_in[10];
  const float* kn_w = (const float*)d_in[11];
  const float* vn_w = (const float*)d_in[12];
  const float* ln_w = (const float*)d_in[13];
  const float* ln_b = (const float*)d_in[14];
  const int* mask = (const int*)d_in[15];

  float* ws = (float*)d_ws;
  // Layout (floats). No live overlap:
  //   xn    [0        , 1048576 )  dead after 5 GEMMs -> reused as rr
  //   qb    [1048576  , 2097152 )  dead after postproc -> reused as y0
  //   kb    [2097152  , 3145728 )  dead after postproc -> reused as y1
  //   vb    [3145728  , 4194304 )  dead after postproc -> reused as y2
  //   apre  [4194304  , 4259840 )
  //   mpre  [4259840  , 4325376 )
  //   tab   [4325376  , 4390912 )
  //   qh    [4390912  , 5439488 )
  //   kh    [5439488  , 6488064 )
  //   vh    [6488064  , 7536640 )
  //   avv   [7536640  , 7602176 )
  //   mvv   [7602176  , 7667712 )
  //   y3    [7667712  , 8716288 )   total ~34.9 MB
  float* xn = ws + 0;
  float* qb = ws + 1048576;
  float* kb = ws + 2097152;
  float* vb = ws + 3145728;
  float* apre = ws + 4194304;
  float* mpre = ws + 4259840;
  float2* tab = (float2*)(ws + 4325376);
  float* qh = ws + 4390912;
  float* kh = ws + 5439488;
  float* vh = ws + 6488064;
  float* avv = ws + 7536640;
  float* mvv = ws + 7602176;
  float* y3 = ws + 7667712;
  float* y0 = qb;
  float* y1 = kb;
  float* y2 = vb;
  float* rr = xn;

  k_rmsnorm_in<<<NTOK, 256, 0, stream>>>(x, in_w, xn);
  k_rope_table<<<128, 256, 0, stream>>>(tab);
  dim3 gBig(32, 8);
  k_gemm_nt<<<gBig, 256, 0, stream>>>(xn, qW, qb, 512);
  k_gemm_nt<<<gBig, 256, 0, stream>>>(xn, kW, kb, 512);
  k_gemm_nt<<<gBig, 256, 0, stream>>>(xn, vW, vb, 512);
  dim3 gSmall(32, 1);
  k_gemm_nt<<<gSmall, 256, 0, stream>>>(xn, aW, apre, 32);
  k_gemm_nt<<<gSmall, 256, 0, stream>>>(xn, mW, mpre, 32);
  k_postproc<<<4096, 256, 0, stream>>>(qb, kb, vb, apre, mpre, ab, mb, kn_w, vn_w, tab,
                                       qh, kh, vh, avv, mvv);
  k_scan<<<64, 256, 0, stream>>>(qh, kh, vh, avv, mvv, mask, y0, y1, y2, y3);
  k_gemm_out<<<gBig, 256, 0, stream>>>(y0, y1, y2, y3, oW, ob, x, rr);
  k_layernorm<<<NTOK, 256, 0, stream>>>(rr, ln_w, ln_b, (float*)d_out);
  (void)in_sizes; (void)n_in; (void)out_size; (void)ws_size;
}

// Round 12
// 792.300 us; speedup vs baseline: 1.2401x; 1.1114x over previous
//
#include <hip/hip_runtime.h>
#include <math.h>

#define SEQT 1024
#define NTOK 2048
#define HIDN 512
#define NHD 8
#define HDIM 64
#define KTSN 4

__device__ __forceinline__ float wred(float v) {
#pragma unroll
  for (int off = 32; off; off >>= 1) v += __shfl_xor(v, off, 64);
  return v;
}

// rotation-allreduce within rows of 16 via DPP (VALU-speed)
template <int CTRL>
__device__ __forceinline__ float rra(float v) {
  return v + __int_as_float(__builtin_amdgcn_update_dpp(
                 0, __float_as_int(v), CTRL, 0xf, 0xf, true));
}
__device__ __forceinline__ float rlane(float v, int l) {
  return __int_as_float(__builtin_amdgcn_readlane(__float_as_int(v), l));
}
// full-wave sum: 4 DPP row_rors (row sums) + 4 readlanes + adds.
__device__ __forceinline__ float wsum64_fast(float v) {
  v = rra<0x121>(v);  // row_ror:1
  v = rra<0x122>(v);  // row_ror:2
  v = rra<0x124>(v);  // row_ror:4
  v = rra<0x128>(v);  // row_ror:8  -> each lane has its 16-lane row sum
  return (rlane(v, 0) + rlane(v, 16)) + (rlane(v, 32) + rlane(v, 48));
}

// ---------------- K1: input RMSNorm (one block per row) ----------------
__global__ __launch_bounds__(256) void k_rmsnorm_in(
    const float* __restrict__ x, const float* __restrict__ w, float* __restrict__ xn) {
  int m = blockIdx.x;
  int tid = threadIdx.x;
  const float* row = x + (size_t)m * HIDN;
  float2 v = *(const float2*)(row + tid * 2);
  float ss = wred(v.x * v.x + v.y * v.y);
  __shared__ float red[4];
  int lane = tid & 63, wv = tid >> 6;
  if (lane == 0) red[wv] = ss;
  __syncthreads();
  float tot = red[0] + red[1] + red[2] + red[3];
  float inv = rsqrtf(tot * (1.0f / HIDN) + 1e-5f);
  float2 wv2 = *(const float2*)(w + tid * 2);
  float2 o;
  o.x = v.x * inv * wv2.x;
  o.y = v.y * inv * wv2.y;
  *(float2*)(xn + (size_t)m * HIDN + tid * 2) = o;
}

// ---------------- K2: C[m][n] = sum_k A[m][k]*B[n][k]  (M=2048, K=512) ----------------
__global__ __launch_bounds__(256) void k_gemm_nt(
    const float* __restrict__ A, const float* __restrict__ B, float* __restrict__ C, int N) {
  __shared__ __align__(16) float As[32][68];
  __shared__ __align__(16) float Bs[32][68];
  int tid = threadIdx.x;
  int m0 = blockIdx.x * 64, n0 = blockIdx.y * 64;
  int tm = tid >> 4, tn = tid & 15;
  float acc[4][4] = {};
  int rr = tid >> 2, cc = (tid & 3) * 8;
  for (int k0 = 0; k0 < HIDN; k0 += 32) {
    const float* s0 = A + (size_t)(m0 + rr) * HIDN + k0 + cc;
    float4 a0 = *(const float4*)s0;
    float4 a1 = *(const float4*)(s0 + 4);
    As[cc + 0][rr] = a0.x; As[cc + 1][rr] = a0.y; As[cc + 2][rr] = a0.z; As[cc + 3][rr] = a0.w;
    As[cc + 4][rr] = a1.x; As[cc + 5][rr] = a1.y; As[cc + 6][rr] = a1.z; As[cc + 7][rr] = a1.w;
    int bn = n0 + rr;
    float4 b0 = make_float4(0.f, 0.f, 0.f, 0.f), b1 = make_float4(0.f, 0.f, 0.f, 0.f);
    if (bn < N) {
      const float* s1 = B + (size_t)bn * HIDN + k0 + cc;
      b0 = *(const float4*)s1;
      b1 = *(const float4*)(s1 + 4);
    }
    Bs[cc + 0][rr] = b0.x; Bs[cc + 1][rr] = b0.y; Bs[cc + 2][rr] = b0.z; Bs[cc + 3][rr] = b0.w;
    Bs[cc + 4][rr] = b1.x; Bs[cc + 5][rr] = b1.y; Bs[cc + 6][rr] = b1.z; Bs[cc + 7][rr] = b1.w;
    __syncthreads();
#pragma unroll
    for (int kk = 0; kk < 32; ++kk) {
      float4 a4 = *(const float4*)&As[kk][tm * 4];
      float4 b4 = *(const float4*)&Bs[kk][tn * 4];
      float aa[4] = {a4.x, a4.y, a4.z, a4.w};
      float bb[4] = {b4.x, b4.y, b4.z, b4.w};
#pragma unroll
      for (int i = 0; i < 4; ++i)
#pragma unroll
        for (int j = 0; j < 4; ++j) acc[i][j] += aa[i] * bb[j];
    }
    __syncthreads();
  }
#pragma unroll
  for (int i = 0; i < 4; ++i) {
    int mr = m0 + tm * 4 + i;
#pragma unroll
    for (int j = 0; j < 4; ++j) {
      int nc = n0 + tn * 4 + j;
      if (nc < N) C[(size_t)mr * N + nc] = acc[i][j];
    }
  }
}

// ---------------- K3a: rope cos/sin table [t][j] ----------------
__global__ __launch_bounds__(256) void k_rope_table(float2* __restrict__ tab) {
  int idx = blockIdx.x * 256 + threadIdx.x;  // 1024*32
  int t = idx >> 5, j = idx & 31;
  float invf = (float)exp2(-(double)j * (13.287712379549449 / 32.0));  // 10000^(-j/32)
  float ang = (float)t * invf;                                         // fp32, matches ref
  double s, c;
  sincos((double)ang, &s, &c);
  tab[idx] = make_float2((float)c, (float)s);
}

// ---------------- K3b: rope(q,k), rmsnorm(k), rmsnorm(v), alpha, mix; transpose ----------------
__global__ __launch_bounds__(256) void k_postproc(
    const float* __restrict__ q_in, const float* __restrict__ k_in, const float* __restrict__ v_in,
    const float* __restrict__ a_pre, const float* __restrict__ m_pre,
    const float* __restrict__ ab, const float* __restrict__ mb,
    const float* __restrict__ kn_w, const float* __restrict__ vn_w,
    const float2* __restrict__ tab,
    float* __restrict__ qh, float* __restrict__ kh, float* __restrict__ vh,
    float* __restrict__ av, float* __restrict__ mv) {
  int wid = blockIdx.x * 4 + (threadIdx.x >> 6);  // one wave per (b,t,h)
  int lane = threadIdx.x & 63;
  int b = wid >> 13;
  int rem = wid & 8191;
  int t = rem >> 3;
  int h = rem & 7;
  size_t src = (size_t)(b * SEQT + t) * HIDN + h * HDIM + lane;
  float qv = q_in[src], kv = k_in[src], vv = v_in[src];
  float2 cs = tab[t * 32 + (lane & 31)];
  float qpart = __shfl_xor(qv, 32, 64);
  float kpart = __shfl_xor(kv, 32, 64);
  float qr = (lane < 32) ? (qv * cs.x - qpart * cs.y) : (qpart * cs.y + qv * cs.x);
  float kr = (lane < 32) ? (kv * cs.x - kpart * cs.y) : (kpart * cs.y + kv * cs.x);
  float kss = wred(kr * kr);
  float kn = kr * rsqrtf(kss * (1.0f / HDIM) + 1e-5f) * kn_w[lane];
  float vss = wred(vv * vv);
  float vn = vv * rsqrtf(vss * (1.0f / HDIM) + 1e-5f) * vn_w[lane];
  size_t dst = ((size_t)(b * NHD + h) * SEQT + t) * HDIM + lane;
  qh[dst] = qr;
  kh[dst] = kn;
  vh[dst] = vn;
  if (lane < 4) {
    int col = h * 4 + lane;
    float pa = a_pre[(size_t)(b * SEQT + t) * 32 + col] + ab[col];
    float al = 1.0f / (1.0f + expf(-pa));
    al = fminf(fmaxf(al, 1e-4f), 0.9995f);
    float pm = m_pre[(size_t)(b * SEQT + t) * 32 + col] + mb[col];
    float mx = pm;
    mx = fmaxf(mx, __shfl_xor(mx, 1, 64));
    mx = fmaxf(mx, __shfl_xor(mx, 2, 64));
    float e = expf(pm - mx);
    float sum = e;
    sum += __shfl_xor(sum, 1, 64);
    sum += __shfl_xor(sum, 2, 64);
    size_t adst = ((size_t)(b * NHD + h) * KTSN + lane) * SEQT + t;
    av[adst] = al;
    mv[adst] = e / sum;
  }
}

// ---------------- K4: sequential scan, FOUR WAVES per (b,h,kt) cell ----------------
// Wave w owns d in [16w, 16w+16); lane = e. h = 16 named floats/lane.
// k|q packed: lanes 0-15 hold the wave's k-slice, 16-31 the q-slice;
// broadcast via v_readlane. One __syncthreads per step, double-buffered
// LDS exchange. NEW (r12): distance-3 named-stage global prefetch (C,D,E)
// so the vmcnt wait never lands on the serial chain; sqb read as float4.
#define G16(X) \
  X(0, 0) X(1, 1) X(2, 2) X(3, 3) X(4, 0) X(5, 1) X(6, 2) X(7, 3) \
  X(8, 0) X(9, 1) X(10, 2) X(11, 3) X(12, 0) X(13, 1) X(14, 2) X(15, 3)

#define DECLH(g, a) float h##g = 0.f;

#define UPDH(g, a)                                \
  {                                               \
    float ks = rlane(kqC, g);                     \
    h##g = fmaf(h##g, ag, ks * vem);              \
    sq##a = fmaf(h##g, h##g, sq##a);              \
  }

#define YUPH(g, a)                                \
  {                                               \
    float qs = rlane(kqC, 16 + (g));              \
    y##a = fmaf(qs, h##g, y##a);                  \
  }

__global__ __launch_bounds__(256, 1) void k_scan(
    const float* __restrict__ qh, const float* __restrict__ kh, const float* __restrict__ vh,
    const float* __restrict__ av, const float* __restrict__ mv, const int* __restrict__ mask,
    float* __restrict__ y0p, float* __restrict__ y1p, float* __restrict__ y2p,
    float* __restrict__ y3p) {
  int c = blockIdx.x;  // (b*NH+h)*KTS + kt
  int kt = c & 3;
  int bh = c >> 2;
  int b = bh >> 3;
  int h = bh & 7;
  int tid = threadIdx.x;
  int w = tid >> 6;    // wave id: owns d in [16w, 16w+16)
  int lane = tid & 63; // = e
  int dbase = w * 16;

  const float* kp = kh + (size_t)bh * SEQT * HDIM;
  const float* qp = qh + (size_t)bh * SEQT * HDIM;
  const float* vp = vh + (size_t)bh * SEQT * HDIM;
  const float* ap = av + (size_t)c * SEQT;
  const float* mp = mv + (size_t)c * SEQT;
  const int* mk = mask + (size_t)b * SEQT;
  float* ysel = (kt == 0) ? y0p : (kt == 1) ? y1p : (kt == 2) ? y2p : y3p;
  float* ypo = ysel + (size_t)(b * SEQT) * HIDN + h * HDIM + lane;

  __shared__ __align__(16) float sqb[2][4];
  __shared__ __align__(16) float ypart[2][4][64];

  G16(DECLH)  // h0..h15
  float gprev = 1.0f;

  // lanes 0-15: k-slice; lanes 16-31: q-slice; lanes 32-63 duplicate 0-31.
  int off = lane & 15;
  const float* kqbase = ((lane >> 4) & 1) ? qp : kp;
  int kqidx = dbase + off;

  // distance-3 prefetch stages: C=step t, D=t+1, E=t+2
  float kqC = kqbase[kqidx];
  float kqD = kqbase[(size_t)1 * HDIM + kqidx];
  float kqE = kqbase[(size_t)2 * HDIM + kqidx];
  float vC = vp[lane];
  float vD = vp[(size_t)1 * HDIM + lane];
  float vE = vp[(size_t)2 * HDIM + lane];
  float aC = ap[0], aD = ap[1], aE = ap[2];
  float mxC = mp[0], mxD = mp[1], mxE = mp[2];
  float mC = (float)mk[0], mD = (float)mk[1], mE = (float)mk[2];

  for (int t = 0; t < SEQT; ++t) {
    int t3 = t + 3;
    if (t3 > SEQT - 1) t3 = SEQT - 1;
    float kqN = kqbase[(size_t)t3 * HDIM + kqidx];
    float vN = vp[(size_t)t3 * HDIM + lane];
    float aN = ap[t3];
    float mxN = mp[t3];
    float mN = (float)mk[t3];

    float ag = aC * gprev;  // deferred norm scale folded into alpha
    float vem = vC * mC;    // mask folded into v
    float sq0 = 0.f, sq1 = 0.f, sq2 = 0.f, sq3 = 0.f;
    G16(UPDH)  // 16 readlane + 32 FMA-class, register-only
    float y0 = 0.f, y1 = 0.f, y2 = 0.f, y3 = 0.f;
    G16(YUPH)  // independent of the sq chain; overlaps the wsum below
    float sqw = wsum64_fast((sq0 + sq1) + (sq2 + sq3));
    float yp = (y0 + y1) + (y2 + y3);

    int P = t & 1;
    if (lane == 0) sqb[P][w] = sqw;
    ypart[P][w][lane] = yp;
    __syncthreads();
    float4 sq4 = *(const float4*)&sqb[P][0];  // one ds_read_b128
    float sqt = (sq4.x + sq4.y) + (sq4.z + sq4.w);
    float g = fminf(16.0f * rsqrtf(sqt), 1.0f);  // c=sqrt(64)*2; sq=0 -> 1
    if (w == 0) {
      float ys = (ypart[P][0][lane] + ypart[P][1][lane]) +
                 (ypart[P][2][lane] + ypart[P][3][lane]);
      ypo[(size_t)t * HIDN] = (mxC * g) * ys;
    }
    gprev = g;

    kqC = kqD; kqD = kqE; kqE = kqN;
    vC = vD; vD = vE; vE = vN;
    aC = aD; aD = aE; aE = aN;
    mxC = mxD; mxD = mxE; mxE = mxN;
    mC = mD; mD = mE; mE = mN;
  }
}

// ---------------- K5: r = x + (sum_kt y) @ oW^T + ob ----------------
__global__ __launch_bounds__(256) void k_gemm_out(
    const float* __restrict__ y0, const float* __restrict__ y1,
    const float* __restrict__ y2, const float* __restrict__ y3,
    const float* __restrict__ oW, const float* __restrict__ ob,
    const float* __restrict__ x, float* __restrict__ r) {
  __shared__ __align__(16) float As[32][68];
  __shared__ __align__(16) float Bs[32][68];
  int tid = threadIdx.x;
  int m0 = blockIdx.x * 64, n0 = blockIdx.y * 64;
  int tm = tid >> 4, tn = tid & 15;
  float acc[4][4] = {};
  int rr = tid >> 2, cc = (tid & 3) * 8;
  for (int k0 = 0; k0 < HIDN; k0 += 32) {
    size_t aoff = (size_t)(m0 + rr) * HIDN + k0 + cc;
#pragma unroll
    for (int half = 0; half < 2; ++half) {
      size_t sh = aoff + half * 4;
      float4 p0 = *(const float4*)(y0 + sh);
      float4 p1 = *(const float4*)(y1 + sh);
      float4 p2 = *(const float4*)(y2 + sh);
      float4 p3 = *(const float4*)(y3 + sh);
      int cbase = cc + half * 4;
      As[cbase + 0][rr] = p0.x + p1.x + p2.x + p3.x;
      As[cbase + 1][rr] = p0.y + p1.y + p2.y + p3.y;
      As[cbase + 2][rr] = p0.z + p1.z + p2.z + p3.z;
      As[cbase + 3][rr] = p0.w + p1.w + p2.w + p3.w;
    }
    const float* s1 = oW + (size_t)(n0 + rr) * HIDN + k0 + cc;
    float4 b0 = *(const float4*)s1;
    float4 b1 = *(const float4*)(s1 + 4);
    Bs[cc + 0][rr] = b0.x; Bs[cc + 1][rr] = b0.y; Bs[cc + 2][rr] = b0.z; Bs[cc + 3][rr] = b0.w;
    Bs[cc + 4][rr] = b1.x; Bs[cc + 5][rr] = b1.y; Bs[cc + 6][rr] = b1.z; Bs[cc + 7][rr] = b1.w;
    __syncthreads();
#pragma unroll
    for (int kk = 0; kk < 32; ++kk) {
      float4 a4 = *(const float4*)&As[kk][tm * 4];
      float4 b4 = *(const float4*)&Bs[kk][tn * 4];
      float aa[4] = {a4.x, a4.y, a4.z, a4.w};
      float bb[4] = {b4.x, b4.y, b4.z, b4.w};
#pragma unroll
      for (int i = 0; i < 4; ++i)
#pragma unroll
        for (int j = 0; j < 4; ++j) acc[i][j] += aa[i] * bb[j];
    }
    __syncthreads();
  }
#pragma unroll
  for (int i = 0; i < 4; ++i) {
    int mr = m0 + tm * 4 + i;
#pragma unroll
    for (int j = 0; j < 4; ++j) {
      int nc = n0 + tn * 4 + j;
      r[(size_t)mr * HIDN + nc] = x[(size_t)mr * HIDN + nc] + acc[i][j] + ob[nc];
    }
  }
}

// ---------------- K6: LayerNorm -> out ----------------
__global__ __launch_bounds__(256) void k_layernorm(
    const float* __restrict__ r, const float* __restrict__ w, const float* __restrict__ bb,
    float* __restrict__ out) {
  int m = blockIdx.x;
  int tid = threadIdx.x;
  const float* row = r + (size_t)m * HIDN;
  float2 v = *(const float2*)(row + tid * 2);
  float s = wred(v.x + v.y);
  float ss = wred(v.x * v.x + v.y * v.y);
  __shared__ float r1[4], r2[4];
  int lane = tid & 63, wv = tid >> 6;
  if (lane == 0) {
    r1[wv] = s;
    r2[wv] = ss;
  }
  __syncthreads();
  float S = r1[0] + r1[1] + r1[2] + r1[3];
  float SS = r2[0] + r2[1] + r2[2] + r2[3];
  float mu = S * (1.0f / HIDN);
  float var = SS * (1.0f / HIDN) - mu * mu;
  float inv = rsqrtf(var + 1e-5f);
  float2 w2 = *(const float2*)(w + tid * 2);
  float2 b2 = *(const float2*)(bb + tid * 2);
  float2 o;
  o.x = (v.x - mu) * inv * w2.x + b2.x;
  o.y = (v.y - mu) * inv * w2.y + b2.y;
  *(float2*)(out + (size_t)m * HIDN + tid * 2) = o;
}

// ---------------- launch ----------------
extern "C" void kernel_launch(void* const* d_in, const int* in_sizes, int n_in,
                              void* d_out, int out_size, void* d_ws, size_t ws_size,
                              hipStream_t stream) {
  const float* x = (const float*)d_in[0];
  const float* in_w = (const float*)d_in[1];
  const float* qW = (const float*)d_in[2];
  const float* kW = (const float*)d_in[3];
  const float* vW = (const float*)d_in[4];
  const float* aW = (const float*)d_in[5];
  const float* ab = (const float*)d_in[6];
  const float* mW = (const float*)d_in[7];
  const float* mb = (const float*)d_in[8];
  const float* oW = (const float*)d_in[9];
  const float* ob = (const float*)d_in[10];
  const float* kn_w = (const float*)d_in[11];
  const float* vn_w = (const float*)d_in[12];
  const float* ln_w = (const float*)d_in[13];
  const float* ln_b = (const float*)d_in[14];
  const int* mask = (const int*)d_in[15];

  float* ws = (float*)d_ws;
  // Layout (floats). No live overlap:
  //   xn    [0        , 1048576 )  dead after 5 GEMMs -> reused as rr
  //   qb    [1048576  , 2097152 )  dead after postproc -> reused as y0
  //   kb    [2097152  , 3145728 )  dead after postproc -> reused as y1
  //   vb    [3145728  , 4194304 )  dead after postproc -> reused as y2
  //   apre  [4194304  , 4259840 )
  //   mpre  [4259840  , 4325376 )
  //   tab   [4325376  , 4390912 )
  //   qh    [4390912  , 5439488 )
  //   kh    [5439488  , 6488064 )
  //   vh    [6488064  , 7536640 )
  //   avv   [7536640  , 7602176 )
  //   mvv   [7602176  , 7667712 )
  //   y3    [7667712  , 8716288 )   total ~34.9 MB
  float* xn = ws + 0;
  float* qb = ws + 1048576;
  float* kb = ws + 2097152;
  float* vb = ws + 3145728;
  float* apre = ws + 4194304;
  float* mpre = ws + 4259840;
  float2* tab = (float2*)(ws + 4325376);
  float* qh = ws + 4390912;
  float* kh = ws + 5439488;
  float* vh = ws + 6488064;
  float* avv = ws + 7536640;
  float* mvv = ws + 7602176;
  float* y3 = ws + 7667712;
  float* y0 = qb;
  float* y1 = kb;
  float* y2 = vb;
  float* rr = xn;

  k_rmsnorm_in<<<NTOK, 256, 0, stream>>>(x, in_w, xn);
  k_rope_table<<<128, 256, 0, stream>>>(tab);
  dim3 gBig(32, 8);
  k_gemm_nt<<<gBig, 256, 0, stream>>>(xn, qW, qb, 512);
  k_gemm_nt<<<gBig, 256, 0, stream>>>(xn, kW, kb, 512);
  k_gemm_nt<<<gBig, 256, 0, stream>>>(xn, vW, vb, 512);
  dim3 gSmall(32, 1);
  k_gemm_nt<<<gSmall, 256, 0, stream>>>(xn, aW, apre, 32);
  k_gemm_nt<<<gSmall, 256, 0, stream>>>(xn, mW, mpre, 32);
  k_postproc<<<4096, 256, 0, stream>>>(qb, kb, vb, apre, mpre, ab, mb, kn_w, vn_w, tab,
                                       qh, kh, vh, avv, mvv);
  k_scan<<<64, 256, 0, stream>>>(qh, kh, vh, avv, mvv, mask, y0, y1, y2, y3);
  k_gemm_out<<<gBig, 256, 0, stream>>>(y0, y1, y2, y3, oW, ob, x, rr);
  k_layernorm<<<NTOK, 256, 0, stream>>>(rr, ln_w, ln_b, (float*)d_out);
  (void)in_sizes; (void)n_in; (void)out_size; (void)ws_size;
}